// Round 12
// baseline (76.337 us; speedup 1.0000x reference)
//
#include <hip/hip_runtime.h>
#include <hip/hip_bf16.h>

#define C_IN    64
#define C_OUT   128
#define HH      112
#define WW      112
#define NB      16
#define KTOT    576      // C_IN * 9
#define NSTEPS  36       // KTOT / 16
#define NPIX    (HH*WW)  // 12544
#define PH      114      // padded spatial dim
#define PPIX    (PH*PH)  // 12996
#define XT_OFF  147456   // bytes: pw occupies [0, 147456)  (128 m x 576 klog x 2B)
#define XT_BYTES ((size_t)NB * PPIX * C_IN * 2)
// band tiling: block (448 thr, 7 waves) = 32 c_out x 14-row band; 7 iters of 14h x 16w
#define BAND_H  14
#define BH_X    18       // halo cols per 16-wide tile
#define B_RECS  288      // 16 halo rows * 18 cols
#define B_BYTES 36864    // 288 recs * 128 B
// fallback tiling (round-2 kernel)
#define TY      8
#define TX      16
#define HALO_X  18
#define HALO_P  180
#define TILES_X 7
#define NTILES  98

typedef __bf16 bf16x8 __attribute__((ext_vector_type(8)));
typedef float  f32x16 __attribute__((ext_vector_type(16)));

static __device__ __forceinline__ unsigned short f2bf(float v) {
    unsigned int u = __builtin_bit_cast(unsigned int, v);
    u = u + 0x7fffu + ((u >> 16) & 1u);   // RNE
    return (unsigned short)(u >> 16);
}

#define GLOAD_LDS(gp, lp) __builtin_amdgcn_global_load_lds( \
    (const __attribute__((address_space(1))) void*)(gp),    \
    (__attribute__((address_space(3))) void*)(lp), 16, 0, 0)

// ---------------- pack spW = weight*mask -> pw[m][klog] bf16 ----------------
// klog = ij*64 + c  (ij = tap, c = channel); k_orig = c*9 + ij.
// A-fragment gather happens at load time: lane reads 16B at m*1152 + t*32 + g*16
// == klog t*16+g*8 .. +7 for M-row m — identical convention to the verified layout.
__global__ __launch_bounds__(256) void pack_w_kernel(
        const float* __restrict__ weight, const float* __restrict__ mask,
        unsigned short* __restrict__ pw) {
    const int m   = blockIdx.x;      // 0..127
    const int tid = threadIdx.x;
    #pragma unroll
    for (int base = 0; base < 512; base += 256) {
        int klog = base + tid;
        int c = klog & 63, ij = klog >> 6;
        int ko = c * 9 + ij;
        pw[m * KTOT + klog] = f2bf(weight[m * KTOT + ko] * mask[m * KTOT + ko]);
    }
    if (tid < 64) {
        int klog = 512 + tid;
        int c = klog & 63, ij = klog >> 6;
        int ko = c * 9 + ij;
        pw[m * KTOT + klog] = f2bf(weight[m * KTOT + ko] * mask[m * KTOT + ko]);
    }
}

// ---------------- pre-pass: x [b][c][h][w] fp32 -> xT [b][hp][wp][c] bf16, zero-padded ----------------
// Thread = one 16B chunk (8 channels of one padded pixel); wave stores 1024B contiguous.
__global__ __launch_bounds__(256) void transpose_x_kernel(
        const float* __restrict__ x, unsigned short* __restrict__ xT) {
    const int b   = blockIdx.y;
    const int idx = blockIdx.x * 256 + threadIdx.x;   // chunk id = rec*8 + s
    if (idx >= PPIX * 8) return;
    const int rec = idx >> 3, s = idx & 7;
    const int hp = rec / PH, wp = rec - hp * PH;
    const int gh = hp - 1, gw = wp - 1;
    const bool valid = (unsigned)gh < (unsigned)HH && (unsigned)gw < (unsigned)WW;
    const float* src = x + (size_t)b * C_IN * (HH * WW) + (size_t)(s * 8) * (HH * WW)
                         + (gh * WW + gw);
    unsigned int w4[4];
    #pragma unroll
    for (int h = 0; h < 4; ++h) {
        float v0 = valid ? src[(size_t)(h * 2    ) * (HH * WW)] : 0.0f;
        float v1 = valid ? src[(size_t)(h * 2 + 1) * (HH * WW)] : 0.0f;
        w4[h] = (unsigned)f2bf(v0) | ((unsigned)f2bf(v1) << 16);
    }
    uint4 o; o.x = w4[0]; o.y = w4[1]; o.z = w4[2]; o.w = w4[3];
    ((uint4*)(xT + ((size_t)b * PPIX + rec) * C_IN))[s] = o;
}

// ---------------- main conv: A fully in registers, B-only LDS double-buffer ----------------
// Block (448 thr, 7 waves) = M-quarter mq (32 c_out) x one 14-row band. Grid 512 = 2 blocks/CU.
// Wave: A for its M-tile in 36 uint4 regs (loaded once from L2); per K-step 1 B ds_read + 1 MFMA.
// 7 iters over 14h x 16w tiles: issue STAGE(it+1)->buf^1, compute, stores, barrier.
__global__ __launch_bounds__(448, 1) void sparse_conv_mq_kernel(
        const unsigned short* __restrict__ xT, const unsigned short* __restrict__ pw,
        const float* __restrict__ bias, float* __restrict__ out) {
    __shared__ __align__(16) unsigned char Bs[2][B_BYTES];   // 73728 B total

    // XCD-bijective swizzle: 512 % 8 == 0; XCD k gets 64 contiguous bids = 2 images
    const int bid  = (blockIdx.x & 7) * 64 + (blockIdx.x >> 3);
    const int b    = bid >> 5;
    const int rem  = bid & 31;
    const int mq   = rem & 3;        // adjacent bids share (b,band) -> same B halo in L2
    const int band = rem >> 2;       // 0..7
    const int h0   = band * BAND_H;
    const int tid  = threadIdx.x;
    const int wave = tid >> 6, l = tid & 63;
    const int g = l >> 5, ln = l & 31;

    const char* xTb = (const char*)xT + (size_t)b * PPIX * (C_IN * 2);
    const uint4* __restrict__ pwv = (const uint4*)pw;

    // ---- A into registers: 36 x 16B (144 VGPR), one M-tile per wave ----
    const int m = mq * 32 + ln;
    uint4 Areg[NSTEPS];
    #pragma unroll
    for (int t = 0; t < NSTEPS; ++t)
        Areg[t] = pwv[(size_t)m * 72 + t * 2 + g];

    // ---- B staging: halo 16 rows x 18 cols at padded (h0, it*16); swizzled source ----
    auto STAGE = [&](int it, unsigned char* dst) {
        const int w0 = it * 16;
        #pragma unroll
        for (int r = 0; r < 5; ++r) {
            int chunk = r * 448 + tid;
            int p = chunk >> 3, s = chunk & 7;
            int yy = p / BH_X, xx = p - yy * BH_X;
            const char* gp = xTb + (size_t)((h0 + yy) * PH + (w0 + xx)) * (C_IN * 2)
                                 + (((s ^ p) & 7) << 4);
            GLOAD_LDS(gp, (char*)dst + r * 7168 + wave * 1024);
        }
        if (tid < 64) {                      // wave 0 exactly (wave-uniform tail)
            int chunk = 5 * 448 + tid;       // 2240..2303
            int p = chunk >> 3, s = chunk & 7;
            int yy = p / BH_X, xx = p - yy * BH_X;
            const char* gp = xTb + (size_t)((h0 + yy) * PH + (w0 + xx)) * (C_IN * 2)
                                 + (((s ^ p) & 7) << 4);
            GLOAD_LDS(gp, (char*)dst + 5 * 7168 + wave * 1024);
        }
    };

    // per-lane pixel in tile: wave owns rows {2w, 2w+1}, cols 0..15
    const int py = 2 * wave + (ln >> 4);
    const int px = ln & 15;

    // bias by accumulator slot, o = mq*32 + mloc
    float bv[16];
    #pragma unroll
    for (int r = 0; r < 16; ++r) {
        int mloc = (r & 3) + 8 * (r >> 2) + 4 * g;
        bv[r] = bias[mq * 32 + mloc];
    }

    STAGE(0, Bs[0]);
    __syncthreads();   // drain B0 (A loads waited on first use)

    const size_t outb = (size_t)b * C_OUT * NPIX;

    #pragma unroll 1
    for (int it = 0; it < 7; ++it) {
        unsigned char* curB = Bs[it & 1];
        unsigned char* nxtB = Bs[(it & 1) ^ 1];
        if (it < 6) STAGE(it + 1, nxtB);   // async; completes during compute

        f32x16 acc;
        #pragma unroll
        for (int r = 0; r < 16; ++r) acc[r] = bv[r];

        #pragma unroll
        for (int t = 0; t < NSTEPS; ++t) {
            const int ij = t >> 2, cs = t & 3;
            const int di = ij / 3, dj = ij - di * 3;
            const int jb = cs * 2 + g;
            const int Pa = (py + di) * BH_X + (px + dj);
            bf16x8 bb = __builtin_bit_cast(bf16x8,
                *(const uint4*)(curB + Pa * 128 + (((jb ^ Pa) & 7) << 4)));
            bf16x8 a = __builtin_bit_cast(bf16x8, Areg[t]);
            acc = __builtin_amdgcn_mfma_f32_32x32x16_bf16(a, bb, acc, 0, 0, 0);
        }

        // ---- stores: C/D col=lane&31 (pixel), row=(r&3)+8*(r>>2)+4*g ----
        #pragma unroll
        for (int r = 0; r < 16; ++r) {
            int mloc = (r & 3) + 8 * (r >> 2) + 4 * g;
            int o = mq * 32 + mloc;
            out[outb + (size_t)o * NPIX + (h0 + py) * WW + it * 16 + px] = acc[r];
        }

        if (it < 6) __syncthreads();   // drains stage vmcnt; next iter reads nxtB
    }
}

// ---------------- fallback (round-2 kernel, adapted to [m][klog] pw) ----------------
__global__ __launch_bounds__(256, 4) void sparse_conv_fb_kernel(
        const float* __restrict__ x, const unsigned short* __restrict__ pw,
        const float* __restrict__ bias, float* __restrict__ out) {
    __shared__ __align__(16) unsigned short xs[HALO_P * C_IN];

    const int bid = blockIdx.x;
    const int b   = bid / NTILES;
    const int t98 = bid % NTILES;
    const int tyi = t98 / TILES_X;
    const int txi = t98 % TILES_X;
    const int h0  = tyi * TY, w0 = txi * TX;
    const int tid = threadIdx.x;

    const float* xb = x + (size_t)b * C_IN * HH * WW;
    {
        const int p  = tid;
        const bool act = p < HALO_P;
        int yy = p / HALO_X;
        int xx = p - yy * HALO_X;
        int gh = h0 + yy - 1, gw = w0 + xx - 1;
        const bool valid = act && (unsigned)gh < (unsigned)HH && (unsigned)gw < (unsigned)WW;
        const float* bp = xb + (gh * WW + gw);
        float v[C_IN];
        #pragma unroll
        for (int c = 0; c < C_IN; ++c)
            v[c] = valid ? bp[c * (HH * WW)] : 0.0f;
        if (act) {
            char* xc = (char*)xs + p * (C_IN * 2);
            #pragma unroll
            for (int j = 0; j < 8; ++j) {
                bf16x8 bvv;
                #pragma unroll
                for (int e = 0; e < 8; ++e) bvv[e] = (__bf16)v[j * 8 + e];
                *(uint4*)(xc + (((j ^ p) & 7) << 4)) = __builtin_bit_cast(uint4, bvv);
            }
        }
    }
    __syncthreads();

    const int wave = tid >> 6, l = tid & 63;
    const int wm = wave >> 1, wn = wave & 1;
    const int g  = l >> 5,  ln = l & 31;

    int P0[2];
    #pragma unroll
    for (int ntp = 0; ntp < 2; ++ntp) {
        int pt = wn * 64 + ntp * 32 + ln;
        P0[ntp] = (pt >> 4) * HALO_X + (pt & 15);
    }

    f32x16 acc[2][2];
    #pragma unroll
    for (int i = 0; i < 2; ++i)
        #pragma unroll
        for (int jq = 0; jq < 2; ++jq)
            #pragma unroll
            for (int q = 0; q < 16; ++q) acc[i][jq][q] = 0.0f;

    const uint4* __restrict__ pwv = (const uint4*)pw;
    const int m0 = (wm * 2 + 0) * 32 + ln;
    const int m1 = (wm * 2 + 1) * 32 + ln;

    #pragma unroll 1
    for (int ij = 0; ij < 9; ++ij) {
        const int di = ij / 3;
        const int dj = ij - di * 3;
        const int P0a = P0[0] + di * HALO_X + dj;
        const int P1a = P0[1] + di * HALO_X + dj;
        #pragma unroll
        for (int cs = 0; cs < 4; ++cs) {
            const int t = ij * 4 + cs;
            bf16x8 a0 = __builtin_bit_cast(bf16x8, pwv[(size_t)m0 * 72 + t * 2 + g]);
            bf16x8 a1 = __builtin_bit_cast(bf16x8, pwv[(size_t)m1 * 72 + t * 2 + g]);
            const int jb = cs * 2 + g;
            bf16x8 b0 = __builtin_bit_cast(bf16x8,
                *(const uint4*)((const char*)xs + P0a * (C_IN * 2) + (((jb ^ P0a) & 7) << 4)));
            bf16x8 b1 = __builtin_bit_cast(bf16x8,
                *(const uint4*)((const char*)xs + P1a * (C_IN * 2) + (((jb ^ P1a) & 7) << 4)));
            acc[0][0] = __builtin_amdgcn_mfma_f32_32x32x16_bf16(a0, b0, acc[0][0], 0, 0, 0);
            acc[0][1] = __builtin_amdgcn_mfma_f32_32x32x16_bf16(a0, b1, acc[0][1], 0, 0, 0);
            acc[1][0] = __builtin_amdgcn_mfma_f32_32x32x16_bf16(a1, b0, acc[1][0], 0, 0, 0);
            acc[1][1] = __builtin_amdgcn_mfma_f32_32x32x16_bf16(a1, b1, acc[1][1], 0, 0, 0);
        }
    }

    const size_t outb = (size_t)b * C_OUT * HH * WW;
    #pragma unroll
    for (int mtp = 0; mtp < 2; ++mtp) {
        #pragma unroll
        for (int r = 0; r < 16; ++r) {
            int mloc = (r & 3) + 8 * (r >> 2) + 4 * g;
            int o = (wm * 2 + mtp) * 32 + mloc;
            float bvv = bias[o];
            #pragma unroll
            for (int ntp = 0; ntp < 2; ++ntp) {
                int p  = wn * 64 + ntp * 32 + ln;
                int gh = h0 + (p >> 4), gw = w0 + (p & 15);
                out[outb + ((size_t)o * HH + gh) * WW + gw] = acc[mtp][ntp][r] + bvv;
            }
        }
    }
}

extern "C" void kernel_launch(void* const* d_in, const int* in_sizes, int n_in,
                              void* d_out, int out_size, void* d_ws, size_t ws_size,
                              hipStream_t stream) {
    const float* x    = (const float*)d_in[0];
    const float* w    = (const float*)d_in[1];
    const float* mk   = (const float*)d_in[2];
    const float* bs   = (const float*)d_in[3];
    float* out        = (float*)d_out;
    unsigned short* pw = (unsigned short*)d_ws;   // [0, 147456)

    pack_w_kernel<<<dim3(C_OUT), dim3(256), 0, stream>>>(w, mk, pw);

    if (ws_size >= (size_t)XT_OFF + XT_BYTES) {
        unsigned short* xT = (unsigned short*)((char*)d_ws + XT_OFF);
        transpose_x_kernel<<<dim3((PPIX * 8 + 255) / 256, NB), dim3(256), 0, stream>>>(x, xT);
        sparse_conv_mq_kernel<<<dim3(512), dim3(448), 0, stream>>>(xT, pw, bs, out);
    } else {
        sparse_conv_fb_kernel<<<dim3(NB * NTILES), dim3(256), 0, stream>>>(x, pw, bs, out);
    }
}

// Round 13
// 65.334 us; speedup vs baseline: 1.1684x; 1.1684x over previous
//
#include <hip/hip_runtime.h>
#include <hip/hip_bf16.h>

#define C_IN    64
#define C_OUT   128
#define HH      112
#define WW      112
#define NB      16
#define KTOT    576      // C_IN * 9
#define NSTEPS  36       // KTOT / 16
#define NPIX    (HH*WW)  // 12544
#define PH      114      // padded spatial dim
#define PPIX    (PH*PH)  // 12996
#define XT_OFF  147456   // bytes: pw occupies [0, 147456)
#define XT_BYTES ((size_t)NB * PPIX * C_IN * 2)
// band tiling: block (448 thr, 7 waves) = 64 c_out x 14-row band; 7 iters of 14h x 16w
#define BAND_H  14
#define BH_X    18       // halo cols per 16-wide tile
#define B_RECS  288      // 16 halo rows * 18 cols
#define A_BYTES 73728    // 36 t * 2 mt * 64 lanes * 16 B
#define B_BYTES 36864    // 288 recs * 128 B
#define TRB     51       // transpose blocks per image
// fallback tiling (round-2 kernel)
#define TY      8
#define TX      16
#define HALO_X  18
#define HALO_P  180
#define TILES_X 7
#define NTILES  98

typedef __bf16 bf16x8 __attribute__((ext_vector_type(8)));
typedef float  f32x16 __attribute__((ext_vector_type(16)));

static __device__ __forceinline__ unsigned short f2bf(float v) {
    unsigned int u = __builtin_bit_cast(unsigned int, v);
    u = u + 0x7fffu + ((u >> 16) & 1u);   // RNE
    return (unsigned short)(u >> 16);
}

#define GLOAD_LDS(gp, lp) __builtin_amdgcn_global_load_lds( \
    (const __attribute__((address_space(1))) void*)(gp),    \
    (__attribute__((address_space(3))) void*)(lp), 16, 0, 0)

// ---------------- fused prep: pack (blocks 0..35) + transpose (blocks 36..851) ----------------
// pack: pw_frag[t][mt][lane] = 16B; k_log(t,g,e)=t*16+g*8+e; ij=k_log>>6, c=k_log&63; k_orig=c*9+ij
// transpose: x [b][c][h][w] fp32 -> xT [b][hp][wp][c] bf16, zero-padded (per-pixel threads)
__global__ __launch_bounds__(256) void prep_kernel(
        const float* __restrict__ weight, const float* __restrict__ mask,
        const float* __restrict__ x,
        unsigned short* __restrict__ pw, unsigned short* __restrict__ xT) {
    const int bx  = blockIdx.x;
    const int tid = threadIdx.x;
    if (bx < NSTEPS) {
        const int t  = bx;
        const int mt = tid >> 6;
        const int l  = tid & 63;
        const int g  = l >> 5;
        const int m  = mt * 32 + (l & 31);
        unsigned int words[4];
        #pragma unroll
        for (int ew = 0; ew < 4; ++ew) {
            unsigned int w2[2];
            #pragma unroll
            for (int h = 0; h < 2; ++h) {
                int e    = ew * 2 + h;
                int klog = t * 16 + g * 8 + e;
                int ij   = klog >> 6;
                int c    = klog & 63;
                int ko   = c * 9 + ij;
                w2[h] = f2bf(weight[m * KTOT + ko] * mask[m * KTOT + ko]);
            }
            words[ew] = w2[0] | (w2[1] << 16);
        }
        uint4 o4; o4.x = words[0]; o4.y = words[1]; o4.z = words[2]; o4.w = words[3];
        ((uint4*)pw)[(t * 4 + mt) * 64 + l] = o4;
    } else {
        const int idx = bx - NSTEPS;
        const int b   = idx / TRB;
        const int pp  = (idx % TRB) * 256 + tid;
        if (pp >= PPIX) return;
        const int hp = pp / PH, wp = pp - hp * PH;
        const int gh = hp - 1, gw = wp - 1;
        const bool valid = (unsigned)gh < (unsigned)HH && (unsigned)gw < (unsigned)WW;
        const float* src = x + (size_t)b * C_IN * (HH * WW) + (gh * WW + gw);
        uint4* dst = (uint4*)(xT + ((size_t)b * PPIX + pp) * C_IN);
        #pragma unroll
        for (int cb = 0; cb < 8; ++cb) {
            unsigned int w4[4];
            #pragma unroll
            for (int h = 0; h < 4; ++h) {
                float v0 = valid ? src[(size_t)(cb * 8 + h * 2    ) * (HH * WW)] : 0.0f;
                float v1 = valid ? src[(size_t)(cb * 8 + h * 2 + 1) * (HH * WW)] : 0.0f;
                w4[h] = (unsigned)f2bf(v0) | ((unsigned)f2bf(v1) << 16);
            }
            uint4 o; o.x = w4[0]; o.y = w4[1]; o.z = w4[2]; o.w = w4[3];
            dst[cb] = o;
        }
    }
}

// ---------------- main conv: A-resident band, dbuf B, counted-vmcnt barriers ----------------
// Block (448 thr, 7 waves) = M-half mh (64 c_out) x one 14-row band. A (73.7 KB) in LDS once.
// Per iter: issue STAGE(it+1)->nxtB (async), 36 K-steps (2 A + 1 B ds_read, 2 MFMA),
// 32 stores, then s_waitcnt vmcnt(32) [staging drained, stores stay in flight] + raw barrier.
__global__ __launch_bounds__(448, 1) void sparse_conv_band_kernel(
        const unsigned short* __restrict__ xT, const unsigned short* __restrict__ pw,
        const float* __restrict__ bias, float* __restrict__ out) {
    __shared__ __align__(16) unsigned char smem[A_BYTES + 2 * B_BYTES];   // 147456 B
    unsigned char* As  = smem;
    unsigned char* Bs0 = smem + A_BYTES;
    unsigned char* Bs1 = smem + A_BYTES + B_BYTES;

    // XCD-bijective swizzle: 256 % 8 == 0; XCD k gets 32 contiguous bids = 2 images
    const int bid  = (blockIdx.x & 7) * 32 + (blockIdx.x >> 3);
    const int b    = bid >> 4;
    const int rem  = bid & 15;
    const int mh   = rem & 1;        // adjacent bids share (b,band) -> same-XCD L2 reuse
    const int band = rem >> 1;       // 0..7
    const int h0   = band * BAND_H;
    const int tid  = threadIdx.x;
    const int wave = tid >> 6, l = tid & 63;
    const int g = l >> 5, ln = l & 31;

    const char* xTb = (const char*)xT + (size_t)b * PPIX * (C_IN * 2);

    // ---- stage A once: 10 full rounds + wave-uniform tail (waves 0-1) ----
    {
        const char* pwb = (const char*)pw;
        #pragma unroll
        for (int r = 0; r < 10; ++r) {
            int c  = r * 448 + tid;          // c = (t*2+mt)*64 + lane
            int t  = c >> 7;
            int mt = (c >> 6) & 1;
            int ll = c & 63;
            const char* gp = pwb + (size_t)((t * 4 + mh * 2 + mt) * 64 + ll) * 16;
            GLOAD_LDS(gp, (char*)As + r * 7168 + wave * 1024);
        }
        if (tid < 128) {                     // waves 0,1 exactly (wave-uniform)
            int c  = 10 * 448 + tid;         // 4480..4607
            int t  = c >> 7;
            int mt = (c >> 6) & 1;
            int ll = c & 63;
            const char* gp = pwb + (size_t)((t * 4 + mh * 2 + mt) * 64 + ll) * 16;
            GLOAD_LDS(gp, (char*)As + 10 * 7168 + wave * 1024);
        }
    }

    // ---- B staging: halo 16 rows x 18 cols at padded (h0, it*16); swizzled source ----
    auto STAGE = [&](int it, unsigned char* dst) {
        const int w0 = it * 16;
        #pragma unroll
        for (int r = 0; r < 5; ++r) {
            int chunk = r * 448 + tid;
            int p = chunk >> 3, s = chunk & 7;
            int yy = p / BH_X, xx = p - yy * BH_X;
            const char* gp = xTb + (size_t)((h0 + yy) * PH + (w0 + xx)) * (C_IN * 2)
                                 + (((s ^ p) & 7) << 4);
            GLOAD_LDS(gp, (char*)dst + r * 7168 + wave * 1024);
        }
        if (tid < 64) {                      // wave 0 exactly (wave-uniform)
            int chunk = 5 * 448 + tid;       // 2240..2303
            int p = chunk >> 3, s = chunk & 7;
            int yy = p / BH_X, xx = p - yy * BH_X;
            const char* gp = xTb + (size_t)((h0 + yy) * PH + (w0 + xx)) * (C_IN * 2)
                                 + (((s ^ p) & 7) << 4);
            GLOAD_LDS(gp, (char*)dst + 5 * 7168 + wave * 1024);
        }
    };

    // per-lane pixel in tile: wave owns rows {2w, 2w+1}, cols 0..15
    const int py = 2 * wave + (ln >> 4);
    const int px = ln & 15;

    // bias by accumulator slot, o = mh*64 + mt*32 + mloc
    float bv[2][16];
    #pragma unroll
    for (int mt = 0; mt < 2; ++mt)
        #pragma unroll
        for (int r = 0; r < 16; ++r) {
            int mloc = (r & 3) + 8 * (r >> 2) + 4 * g;
            bv[mt][r] = bias[mh * 64 + mt * 32 + mloc];
        }

    STAGE(0, Bs0);
    __syncthreads();   // full drain once: A + B0 resident

    const size_t outb = (size_t)b * C_OUT * NPIX;

    #pragma unroll 1
    for (int it = 0; it < 7; ++it) {
        unsigned char* curB = (it & 1) ? Bs1 : Bs0;
        unsigned char* nxtB = (it & 1) ? Bs0 : Bs1;
        if (it < 6) STAGE(it + 1, nxtB);   // async; completes during compute

        f32x16 acc[2];
        #pragma unroll
        for (int mt = 0; mt < 2; ++mt)
            #pragma unroll
            for (int r = 0; r < 16; ++r) acc[mt][r] = bv[mt][r];

        #pragma unroll
        for (int t = 0; t < NSTEPS; ++t) {
            const int ij = t >> 2, cs = t & 3;
            const int di = ij / 3, dj = ij - di * 3;
            const int jb = cs * 2 + g;
            bf16x8 a0 = __builtin_bit_cast(bf16x8,
                *(const uint4*)(As + ((t * 2 + 0) * 64 + l) * 16));
            bf16x8 a1 = __builtin_bit_cast(bf16x8,
                *(const uint4*)(As + ((t * 2 + 1) * 64 + l) * 16));
            const int Pa = (py + di) * BH_X + (px + dj);
            bf16x8 bb = __builtin_bit_cast(bf16x8,
                *(const uint4*)(curB + Pa * 128 + (((jb ^ Pa) & 7) << 4)));
            acc[0] = __builtin_amdgcn_mfma_f32_32x32x16_bf16(a0, bb, acc[0], 0, 0, 0);
            acc[1] = __builtin_amdgcn_mfma_f32_32x32x16_bf16(a1, bb, acc[1], 0, 0, 0);
        }

        // ---- stores: C/D col=lane&31 (pixel), row=(r&3)+8*(r>>2)+4*g ----
        #pragma unroll
        for (int mt = 0; mt < 2; ++mt)
            #pragma unroll
            for (int r = 0; r < 16; ++r) {
                int mloc = (r & 3) + 8 * (r >> 2) + 4 * g;
                int o = mh * 64 + mt * 32 + mloc;
                out[outb + (size_t)o * NPIX + (h0 + py) * WW + it * 16 + px] = acc[mt][r];
            }

        if (it < 6) {
            // counted drain: issue order was {<=6 staging gload_lds, 32 stores}.
            // vmcnt(32) -> staging complete; stores keep flying across the barrier.
            asm volatile("s_waitcnt vmcnt(32)" ::: "memory");
            __builtin_amdgcn_sched_barrier(0);
            __builtin_amdgcn_s_barrier();
        }
    }
}

// ---------------- fallback (round-2 kernel) if ws too small for xT ----------------
__global__ __launch_bounds__(256, 4) void sparse_conv_fb_kernel(
        const float* __restrict__ x, const unsigned short* __restrict__ pw,
        const float* __restrict__ bias, float* __restrict__ out) {
    __shared__ __align__(16) unsigned short xs[HALO_P * C_IN];

    const int bid = blockIdx.x;
    const int b   = bid / NTILES;
    const int t98 = bid % NTILES;
    const int tyi = t98 / TILES_X;
    const int txi = t98 % TILES_X;
    const int h0  = tyi * TY, w0 = txi * TX;
    const int tid = threadIdx.x;

    const float* xb = x + (size_t)b * C_IN * HH * WW;
    {
        const int p  = tid;
        const bool act = p < HALO_P;
        int yy = p / HALO_X;
        int xx = p - yy * HALO_X;
        int gh = h0 + yy - 1, gw = w0 + xx - 1;
        const bool valid = act && (unsigned)gh < (unsigned)HH && (unsigned)gw < (unsigned)WW;
        const float* bp = xb + (gh * WW + gw);
        float v[C_IN];
        #pragma unroll
        for (int c = 0; c < C_IN; ++c)
            v[c] = valid ? bp[c * (HH * WW)] : 0.0f;
        if (act) {
            char* xc = (char*)xs + p * (C_IN * 2);
            #pragma unroll
            for (int j = 0; j < 8; ++j) {
                bf16x8 bvv;
                #pragma unroll
                for (int e = 0; e < 8; ++e) bvv[e] = (__bf16)v[j * 8 + e];
                *(uint4*)(xc + (((j ^ p) & 7) << 4)) = __builtin_bit_cast(uint4, bvv);
            }
        }
    }
    __syncthreads();

    const int wave = tid >> 6, l = tid & 63;
    const int wm = wave >> 1, wn = wave & 1;
    const int g  = l >> 5,  ln = l & 31;

    int P0[2];
    #pragma unroll
    for (int ntp = 0; ntp < 2; ++ntp) {
        int pt = wn * 64 + ntp * 32 + ln;
        P0[ntp] = (pt >> 4) * HALO_X + (pt & 15);
    }

    f32x16 acc[2][2];
    #pragma unroll
    for (int i = 0; i < 2; ++i)
        #pragma unroll
        for (int jq = 0; jq < 2; ++jq)
            #pragma unroll
            for (int q = 0; q < 16; ++q) acc[i][jq][q] = 0.0f;

    const uint4* __restrict__ pwv = (const uint4*)pw;

    #pragma unroll 1
    for (int ij = 0; ij < 9; ++ij) {
        const int di = ij / 3;
        const int dj = ij - di * 3;
        const int P0a = P0[0] + di * HALO_X + dj;
        const int P1a = P0[1] + di * HALO_X + dj;
        #pragma unroll
        for (int cs = 0; cs < 4; ++cs) {
            const int t = ij * 4 + cs;
            bf16x8 a0 = __builtin_bit_cast(bf16x8, pwv[(t * 4 + wm * 2 + 0) * 64 + l]);
            bf16x8 a1 = __builtin_bit_cast(bf16x8, pwv[(t * 4 + wm * 2 + 1) * 64 + l]);
            const int jb = cs * 2 + g;
            bf16x8 b0 = __builtin_bit_cast(bf16x8,
                *(const uint4*)((const char*)xs + P0a * (C_IN * 2) + (((jb ^ P0a) & 7) << 4)));
            bf16x8 b1 = __builtin_bit_cast(bf16x8,
                *(const uint4*)((const char*)xs + P1a * (C_IN * 2) + (((jb ^ P1a) & 7) << 4)));
            acc[0][0] = __builtin_amdgcn_mfma_f32_32x32x16_bf16(a0, b0, acc[0][0], 0, 0, 0);
            acc[0][1] = __builtin_amdgcn_mfma_f32_32x32x16_bf16(a0, b1, acc[0][1], 0, 0, 0);
            acc[1][0] = __builtin_amdgcn_mfma_f32_32x32x16_bf16(a1, b0, acc[1][0], 0, 0, 0);
            acc[1][1] = __builtin_amdgcn_mfma_f32_32x32x16_bf16(a1, b1, acc[1][1], 0, 0, 0);
        }
    }

    const size_t outb = (size_t)b * C_OUT * HH * WW;
    #pragma unroll
    for (int mtp = 0; mtp < 2; ++mtp) {
        #pragma unroll
        for (int r = 0; r < 16; ++r) {
            int mloc = (r & 3) + 8 * (r >> 2) + 4 * g;
            int o = (wm * 2 + mtp) * 32 + mloc;
            float bvv = bias[o];
            #pragma unroll
            for (int ntp = 0; ntp < 2; ++ntp) {
                int p  = wn * 64 + ntp * 32 + ln;
                int gh = h0 + (p >> 4), gw = w0 + (p & 15);
                out[outb + ((size_t)o * HH + gh) * WW + gw] = acc[mtp][ntp][r] + bvv;
            }
        }
    }
}

extern "C" void kernel_launch(void* const* d_in, const int* in_sizes, int n_in,
                              void* d_out, int out_size, void* d_ws, size_t ws_size,
                              hipStream_t stream) {
    const float* x    = (const float*)d_in[0];
    const float* w    = (const float*)d_in[1];
    const float* mk   = (const float*)d_in[2];
    const float* bs   = (const float*)d_in[3];
    float* out        = (float*)d_out;
    unsigned short* pw = (unsigned short*)d_ws;   // [0, 147456)

    if (ws_size >= (size_t)XT_OFF + XT_BYTES) {
        unsigned short* xT = (unsigned short*)((char*)d_ws + XT_OFF);
        prep_kernel<<<dim3(NSTEPS + NB * TRB), dim3(256), 0, stream>>>(w, mk, x, pw, xT);
        sparse_conv_band_kernel<<<dim3(256), dim3(448), 0, stream>>>(xT, pw, bs, out);
    } else {
        prep_kernel<<<dim3(NSTEPS), dim3(256), 0, stream>>>(w, mk, x, pw, (unsigned short*)pw);
        sparse_conv_fb_kernel<<<dim3(NB * NTILES), dim3(256), 0, stream>>>(x, pw, bs, out);
    }
}